// Round 1
// 3824.837 us; speedup vs baseline: 1.0264x; 1.0264x over previous
//
#include <hip/hip_runtime.h>

#define Bn 2048
#define Hn 1024
#define Ln 96
#define Vn 96

typedef short bf16x8 __attribute__((ext_vector_type(8)));
typedef float f32x4 __attribute__((ext_vector_type(4)));

// counted waits (T4): immediates must be literals
#define VM_WAIT(n) asm volatile("s_waitcnt vmcnt(" #n ")" ::: "memory")
#define LGKM_WAIT0 asm volatile("s_waitcnt lgkmcnt(0)" ::: "memory")

__device__ __forceinline__ void async16(const void* g, void* l)
{
    __builtin_amdgcn_global_load_lds(
        (const __attribute__((address_space(1))) void*)g,
        (__attribute__((address_space(3))) void*)l, 16, 0, 0);
}

__device__ __forceinline__ unsigned short f2bf(float f)
{
    unsigned u = __float_as_uint(f);
    u += 0x7fff + ((u >> 16) & 1);          // round-to-nearest-even
    return (unsigned short)(u >> 16);
}

__device__ __forceinline__ float bf2f(unsigned short s)
{
    return __uint_as_float(((unsigned)s) << 16);
}

__device__ __forceinline__ float fast_tanh(float x)
{
    float e = __expf(2.0f * x);
    return 1.0f - __fdividef(2.0f, e + 1.0f);
}

// ---------------------------------------------------------------------------
// Fused step kernel, launch index s (0..97):
//   blocks [0,512)    : L1(t=s-1)  h1(t) = tanh(h0(t)Wi^T + h1(t-1)Wh^T + b)
//   blocks [512,1024) : L0(t=s)    h0(t) = tanh(h0(t-1)W0^T + x_t*wih + b)
//   blocks [1024,1056): FC(t=s-2)  out(t) = h1(t) fcW^T + fcb
// K-loop is BARRIER-FREE: each wave stages into and reads only its own LDS
// region, so ordering is per-wave counted vmcnt(8/10) (loads stay in flight
// across iterations) + lgkmcnt(0) before overwriting the buffer read last
// iteration. LDS fragment slots are XOR-swizzled (slot ^= (row>>1)&3) on BOTH
// the global source address and the ds_read address -> ds_read_b128 goes from
// 8-way to 2-way (free) bank aliasing.
// LDS: A = 2 waves x dbuf x 64x32 bf16 (16 KB), B = 2 x dbuf x 96x32 (24 KB)
//      epilogue f32 areas alias A (16 KB) and B (24 KB). 40 KB -> 4 blk/CU.
// ---------------------------------------------------------------------------
__global__ __launch_bounds__(128, 2) void fused_step(
    int s,
    const unsigned short* __restrict__ H0rd, unsigned short* __restrict__ H0wr,
    const unsigned short* __restrict__ H1rd, unsigned short* __restrict__ H1wr,
    const unsigned short* __restrict__ W0b,
    const unsigned short* __restrict__ W1ib, const unsigned short* __restrict__ W1hb,
    const unsigned short* __restrict__ fcWb,
    const float* __restrict__ w0ih,
    const float* __restrict__ b0i, const float* __restrict__ b0h,
    const float* __restrict__ b1i, const float* __restrict__ b1h,
    const float* __restrict__ fcb, const float* __restrict__ x,
    float* __restrict__ out)
{
    __shared__ __align__(16) unsigned short smem[20480];   // 40 KB
    const int tid = threadIdx.x;
    const int lane = tid & 63;
    const int wave = tid >> 6;
    const int srow = lane >> 2;                 // staging row within 16-row chunk
    // stage-side swizzle: lane (row=srow, stored slot=lane&3) fetches global
    // slot (lane&3) ^ g(row), g(row) = (row>>1)&3  [bijective per row]
    const int scol = ((lane & 3) ^ ((lane >> 3) & 3)) * 8;  // bf16 elems
    const int lr = lane & 15;
    const int lq = lane >> 4;
    // read-side swizzle: global slot lq of row lr lives at stored slot lq^g(lr)
    const int roff = lr * 32 + ((lq ^ ((lr >> 1) & 3)) * 8);
    unsigned short* Al = smem + wave * 4096;           // + buf*2048
    unsigned short* Bl = smem + 8192 + wave * 6144;    // + buf*3072
    const int bid = blockIdx.x;

    if (bid < 512) {
        // ================= L1(t = s-1), dual GEMM split across waves ======
        if (s < 1 || s > 96) return;
        const int bBase = (bid >> 4) * 64;
        const int iBase = (bid & 15) * 64;
        const unsigned short* Ag = wave ? H1rd : H0rd;
        const unsigned short* Bg = wave ? W1hb : W1ib;

        f32x4 acc[4][4];
#pragma unroll
        for (int i = 0; i < 4; ++i)
#pragma unroll
            for (int j = 0; j < 4; ++j) acc[i][j] = (f32x4){0.f, 0.f, 0.f, 0.f};

#pragma unroll
        for (int c = 0; c < 4; ++c) {
            async16(Ag + (size_t)(bBase + c * 16 + srow) * Hn + scol, Al + c * 512);
            async16(Bg + (size_t)(iBase + c * 16 + srow) * Hn + scol, Bl + c * 512);
        }
        int buf = 0;
        for (int it = 0; it < 32; ++it) {
            if (it + 1 < 32) {
                LGKM_WAIT0;   // prev iter's ds_reads of buf^1 fully retired
                const int kt = (it + 1) * 32;
#pragma unroll
                for (int c = 0; c < 4; ++c) {
                    async16(Ag + (size_t)(bBase + c * 16 + srow) * Hn + kt + scol,
                            Al + (buf ^ 1) * 2048 + c * 512);
                    async16(Bg + (size_t)(iBase + c * 16 + srow) * Hn + kt + scol,
                            Bl + (buf ^ 1) * 3072 + c * 512);
                }
                VM_WAIT(8);   // 8 newest stay in flight; buf's 8 are complete
            } else {
                VM_WAIT(0);
            }
            bf16x8 a[4], b[4];
#pragma unroll
            for (int i = 0; i < 4; ++i) {
                a[i] = *(const bf16x8*)(Al + buf * 2048 + i * 512 + roff);
                b[i] = *(const bf16x8*)(Bl + buf * 3072 + i * 512 + roff);
            }
            __builtin_amdgcn_s_setprio(1);
#pragma unroll
            for (int mt = 0; mt < 4; ++mt)
#pragma unroll
                for (int nt = 0; nt < 4; ++nt)
                    acc[mt][nt] = __builtin_amdgcn_mfma_f32_16x16x32_bf16(
                        a[mt], b[nt], acc[mt][nt], 0, 0, 0);
            __builtin_amdgcn_s_setprio(0);
            buf ^= 1;
        }
        __syncthreads();                        // both waves done with staging LDS
        {
            float* myred = (float*)(wave ? (smem + 8192) : smem);
#pragma unroll
            for (int mt = 0; mt < 4; ++mt)
#pragma unroll
                for (int nt = 0; nt < 4; ++nt)
#pragma unroll
                    for (int r = 0; r < 4; ++r)
                        myred[(mt * 16 + lq * 4 + r) * 64 + nt * 16 + lr] = acc[mt][nt][r];
        }
        __syncthreads();
        {
            const float* rA = (const float*)smem;
            const float* rB = (const float*)(smem + 8192);
            const int n = iBase + lane;
            const float bs = b1i[n] + b1h[n];
#pragma unroll 8
            for (int rr = 0; rr < 32; ++rr) {
                const int row = wave * 32 + rr;
                float v = rA[row * 64 + lane] + rB[row * 64 + lane] + bs;
                H1wr[(size_t)(bBase + row) * Hn + n] = f2bf(fast_tanh(v));
            }
        }
    } else if (bid < 1024) {
        // ================= L0(t = s), split-K across waves ================
        if (s > 95) return;
        const int idx = bid - 512;
        const int bBase = (idx >> 4) * 64;
        const int iBase = (idx & 15) * 64;
        const int k0 = wave * 512;
        const unsigned short* Ag = H0rd;
        const unsigned short* Bg = W0b;

        f32x4 acc[4][4];
#pragma unroll
        for (int i = 0; i < 4; ++i)
#pragma unroll
            for (int j = 0; j < 4; ++j) acc[i][j] = (f32x4){0.f, 0.f, 0.f, 0.f};

#pragma unroll
        for (int c = 0; c < 4; ++c) {
            async16(Ag + (size_t)(bBase + c * 16 + srow) * Hn + k0 + scol, Al + c * 512);
            async16(Bg + (size_t)(iBase + c * 16 + srow) * Hn + k0 + scol, Bl + c * 512);
        }
        int buf = 0;
        for (int it = 0; it < 16; ++it) {
            if (it + 1 < 16) {
                LGKM_WAIT0;
                const int kt = k0 + (it + 1) * 32;
#pragma unroll
                for (int c = 0; c < 4; ++c) {
                    async16(Ag + (size_t)(bBase + c * 16 + srow) * Hn + kt + scol,
                            Al + (buf ^ 1) * 2048 + c * 512);
                    async16(Bg + (size_t)(iBase + c * 16 + srow) * Hn + kt + scol,
                            Bl + (buf ^ 1) * 3072 + c * 512);
                }
                VM_WAIT(8);
            } else {
                VM_WAIT(0);
            }
            bf16x8 a[4], b[4];
#pragma unroll
            for (int i = 0; i < 4; ++i) {
                a[i] = *(const bf16x8*)(Al + buf * 2048 + i * 512 + roff);
                b[i] = *(const bf16x8*)(Bl + buf * 3072 + i * 512 + roff);
            }
            __builtin_amdgcn_s_setprio(1);
#pragma unroll
            for (int mt = 0; mt < 4; ++mt)
#pragma unroll
                for (int nt = 0; nt < 4; ++nt)
                    acc[mt][nt] = __builtin_amdgcn_mfma_f32_16x16x32_bf16(
                        a[mt], b[nt], acc[mt][nt], 0, 0, 0);
            __builtin_amdgcn_s_setprio(0);
            buf ^= 1;
        }
        __syncthreads();
        {
            float* myred = (float*)(wave ? (smem + 8192) : smem);
#pragma unroll
            for (int mt = 0; mt < 4; ++mt)
#pragma unroll
                for (int nt = 0; nt < 4; ++nt)
#pragma unroll
                    for (int r = 0; r < 4; ++r)
                        myred[(mt * 16 + lq * 4 + r) * 64 + nt * 16 + lr] = acc[mt][nt][r];
        }
        __syncthreads();
        {
            const float* rA = (const float*)smem;
            const float* rB = (const float*)(smem + 8192);
            const int n = iBase + lane;
            const float wv = w0ih[n];
            const float bs = b0i[n] + b0h[n];
#pragma unroll 8
            for (int rr = 0; rr < 32; ++rr) {
                const int row = wave * 32 + rr;
                const int bb = bBase + row;
                const float xv = x[bb * Ln + s];
                float v = rA[row * 64 + lane] + rB[row * 64 + lane] + xv * wv + bs;
                H0wr[(size_t)bb * Hn + n] = f2bf(fast_tanh(v));
            }
        }
    } else {
        // ================= FC(t = s-2), split-K across waves ==============
        if (s < 2) return;
        const int t = s - 2;
        const int bBase = (bid - 1024) * 64;
        const int k0 = wave * 512;
        const unsigned short* Ag = H1rd;
        const unsigned short* Bg = fcWb;
        float* red = (float*)(smem + 8192);    // 24 KB reduce area (B region)

        f32x4 acc[4][6];
#pragma unroll
        for (int i = 0; i < 4; ++i)
#pragma unroll
            for (int j = 0; j < 6; ++j) acc[i][j] = (f32x4){0.f, 0.f, 0.f, 0.f};

#pragma unroll
        for (int c = 0; c < 4; ++c)
            async16(Ag + (size_t)(bBase + c * 16 + srow) * Hn + k0 + scol, Al + c * 512);
#pragma unroll
        for (int c = 0; c < 6; ++c)
            async16(Bg + (size_t)(c * 16 + srow) * Hn + k0 + scol, Bl + c * 512);
        int buf = 0;
        for (int it = 0; it < 16; ++it) {
            if (it + 1 < 16) {
                LGKM_WAIT0;
                const int kt = k0 + (it + 1) * 32;
#pragma unroll
                for (int c = 0; c < 4; ++c)
                    async16(Ag + (size_t)(bBase + c * 16 + srow) * Hn + kt + scol,
                            Al + (buf ^ 1) * 2048 + c * 512);
#pragma unroll
                for (int c = 0; c < 6; ++c)
                    async16(Bg + (size_t)(c * 16 + srow) * Hn + kt + scol,
                            Bl + (buf ^ 1) * 3072 + c * 512);
                VM_WAIT(10);
            } else {
                VM_WAIT(0);
            }
            bf16x8 a[4], b[6];
#pragma unroll
            for (int i = 0; i < 4; ++i)
                a[i] = *(const bf16x8*)(Al + buf * 2048 + i * 512 + roff);
#pragma unroll
            for (int i = 0; i < 6; ++i)
                b[i] = *(const bf16x8*)(Bl + buf * 3072 + i * 512 + roff);
            __builtin_amdgcn_s_setprio(1);
#pragma unroll
            for (int mt = 0; mt < 4; ++mt)
#pragma unroll
                for (int nt = 0; nt < 6; ++nt)
                    acc[mt][nt] = __builtin_amdgcn_mfma_f32_16x16x32_bf16(
                        a[mt], b[nt], acc[mt][nt], 0, 0, 0);
            __builtin_amdgcn_s_setprio(0);
            buf ^= 1;
        }
        __syncthreads();
        if (wave == 1) {
#pragma unroll
            for (int mt = 0; mt < 4; ++mt)
#pragma unroll
                for (int nt = 0; nt < 6; ++nt)
#pragma unroll
                    for (int r = 0; r < 4; ++r)
                        red[(mt * 16 + lq * 4 + r) * 96 + nt * 16 + lr] = acc[mt][nt][r];
        }
        __syncthreads();
        if (wave == 0) {
#pragma unroll
            for (int mt = 0; mt < 4; ++mt)
#pragma unroll
                for (int r = 0; r < 4; ++r) {
                    const int row = mt * 16 + lq * 4 + r;
                    const size_t o = (size_t)(bBase + row) * (Ln * Vn) + (size_t)t * Vn;
#pragma unroll
                    for (int nt = 0; nt < 6; ++nt) {
                        const int v = nt * 16 + lr;
                        out[o + v] = acc[mt][nt][r] + red[row * 96 + v] + fcb[v];
                    }
                }
        }
    }
}

// ---------------------------------------------------------------------------
__global__ void f32_to_bf16(const float* __restrict__ in,
                            unsigned short* __restrict__ out, int n)
{
    int i = blockIdx.x * blockDim.x + threadIdx.x;
    int stride = gridDim.x * blockDim.x;
    for (; i < n; i += stride) out[i] = f2bf(in[i]);
}

__global__ void hidden_out(const unsigned short* __restrict__ h0,
                           const unsigned short* __restrict__ h1,
                           float* __restrict__ out)
{
    int i = blockIdx.x * 256 + threadIdx.x;
    out[i] = bf2f(h0[i]);
    out[(size_t)Bn * Hn + i] = bf2f(h1[i]);
}

// ---------------------------------------------------------------------------
// Sequential probability adjustment. One wave per row. Changes vs prior:
//   (a) prefetch row t+1 before the argmax chain of row t (hides LLC latency)
//   (b) only write the (rare) modified elements (cols 0/1) — the buffer
//       already holds the correct FC logits everywhere else.
// ---------------------------------------------------------------------------
__device__ __forceinline__ int wave_argmax(float v0, float v1, int lane)
{
    float bv = v0;
    int bi = lane;
    if (v1 > bv) { bv = v1; bi = 64 + lane; }
#pragma unroll
    for (int off = 32; off > 0; off >>= 1) {
        float ov = __shfl_xor(bv, off);
        int oi = __shfl_xor(bi, off);
        if (ov > bv || (ov == bv && oi < bi)) { bv = ov; bi = oi; }
    }
    return bi;
}

__global__ __launch_bounds__(256) void adjust_kernel(float* __restrict__ out)
{
    const int gtid = blockIdx.x * 256 + threadIdx.x;
    const int b = gtid >> 6;
    const int lane = threadIdx.x & 63;
    if (b >= Bn) return;
    float* row = out + (size_t)b * (Ln * Vn);

    float v0 = row[lane];
    float v1 = (lane < 32) ? row[64 + lane] : -1e30f;
    int prev_arg = wave_argmax(v0, v1, lane);

    // prefetch row 1
    float n0 = row[Vn + lane];
    float n1 = (lane < 32) ? row[Vn + 64 + lane] : -1e30f;

    for (int t = 1; t < Ln; ++t) {
        float cv0 = n0, cv1 = n1;
        if (t + 1 < Ln) {                       // prefetch row t+1
            n0 = row[(t + 1) * Vn + lane];
            n1 = (lane < 32) ? row[(t + 1) * Vn + 64 + lane] : -1e30f;
        }
        int cur_arg = wave_argmax(cv0, cv1, lane);
        bool wrote = false;
        if ((prev_arg == 0) && (cur_arg != 1) && lane == 1) { cv0 += 0.5f; wrote = true; }
        if ((t == Ln - 1) && (cur_arg == 0) && lane == 0)   { cv0 -= 0.5f; wrote = true; }
        if (wrote) row[t * Vn + lane] = cv0;
        if (t + 1 < Ln) prev_arg = wave_argmax(cv0, cv1, lane);
    }
}

// ---------------------------------------------------------------------------
extern "C" void kernel_launch(void* const* d_in, const int* in_sizes, int n_in,
                              void* d_out, int out_size, void* d_ws, size_t ws_size,
                              hipStream_t stream)
{
    const float* x    = (const float*)d_in[0];
    const float* w0ih = (const float*)d_in[1];
    const float* W0   = (const float*)d_in[2];
    const float* b0i  = (const float*)d_in[3];
    const float* b0h  = (const float*)d_in[4];
    const float* W1i  = (const float*)d_in[5];
    const float* W1h  = (const float*)d_in[6];
    const float* b1i  = (const float*)d_in[7];
    const float* b1h  = (const float*)d_in[8];
    const float* fcW  = (const float*)d_in[9];
    const float* fcb  = (const float*)d_in[10];
    float* out = (float*)d_out;

    const size_t HH = (size_t)Hn * Hn;
    const size_t BH = (size_t)Bn * Hn;
    unsigned short* ws = (unsigned short*)d_ws;
    unsigned short* W0b  = ws;
    unsigned short* W1ib = ws + HH;
    unsigned short* W1hb = ws + 2 * HH;
    unsigned short* fcWb = ws + 3 * HH;
    unsigned short* H0[2] = { ws + 4 * HH,          ws + 4 * HH + BH };
    unsigned short* H1[2] = { ws + 4 * HH + 2 * BH, ws + 4 * HH + 3 * BH };

    // h0(-1) lives in H0[0], h1(-1) in H1[0] (read at s=0 / s=1): zero them.
    hipMemsetAsync(H0[0], 0, BH * sizeof(unsigned short), stream);
    hipMemsetAsync(H1[0], 0, BH * sizeof(unsigned short), stream);

    f32_to_bf16<<<dim3(512), dim3(256), 0, stream>>>(W0,  W0b,  (int)HH);
    f32_to_bf16<<<dim3(512), dim3(256), 0, stream>>>(W1i, W1ib, (int)HH);
    f32_to_bf16<<<dim3(512), dim3(256), 0, stream>>>(W1h, W1hb, (int)HH);
    f32_to_bf16<<<dim3(64),  dim3(256), 0, stream>>>(fcW, fcWb, Vn * Hn);

    // Launch s computes: L0(s) [s<=95], L1(s-1) [s>=1], FC(s-2) [s>=2].
    // h0(t) lives in H0[(t+1)&1]; h1(t) in H1[(t+1)&1].
    for (int s = 0; s <= 97; ++s) {
        fused_step<<<dim3(1056), dim3(128), 0, stream>>>(
            s,
            H0[s & 1], H0[(s + 1) & 1],          // L0 read / write
            H1[(s + 1) & 1], H1[s & 1],          // h1(s-2) read / h1(s-1) write
            W0b, W1ib, W1hb, fcWb,
            w0ih, b0i, b0h, b1i, b1h, fcb, x, out);
    }

    adjust_kernel<<<dim3(512), dim3(256), 0, stream>>>(out);

    // final states: h0(95) = H0[0], h1(95) = H1[0]
    hidden_out<<<dim3((int)(BH / 256)), dim3(256), 0, stream>>>(
        H0[0], H1[0], out + (size_t)Bn * Ln * Vn);
}